// Round 1
// baseline (1626.024 us; speedup 1.0000x reference)
//
#include <hip/hip_runtime.h>
#include <math.h>

#define LL 16384
#define HH 1024
#define PP 512
#define CHUNK 64        // scan chunk length T
#define NCHUNK 256      // LL / CHUNK

// ---------------------------------------------------------------------------
// Kernel 0: discretization constants per p:
//   Lambda_bar = exp(Lambda * Delta), gamma = (Lambda_bar - 1)/Lambda,
//   lamT = Lambda_bar^CHUNK (for chunk-carry scan)
// ---------------------------------------------------------------------------
__global__ void k_setup(const float* __restrict__ lre, const float* __restrict__ lim,
                        const float* __restrict__ logstep,
                        float* __restrict__ gre, float* __restrict__ gim,
                        float* __restrict__ lbre, float* __restrict__ lbim,
                        float* __restrict__ ltre, float* __restrict__ ltim) {
    int p = threadIdx.x;
    if (p >= PP) return;
    float dt = expf(logstep[p]);           // STEP_RESCALE = 1
    float ar = lre[p], ai = lim[p];
    float e = expf(ar * dt);
    float s, c;
    sincosf(ai * dt, &s, &c);
    float Lr = e * c, Li = e * s;          // Lambda_bar
    lbre[p] = Lr; lbim[p] = Li;
    // gamma = (Lambda_bar - 1) / Lambda   (complex divide)
    float nr = Lr - 1.0f, ni = Li;
    float den = ar * ar + ai * ai;
    gre[p] = (nr * ar + ni * ai) / den;
    gim[p] = (ni * ar - nr * ai) / den;
    // lamT = Lambda_bar^64 via 6 squarings
    float tr = Lr, ti = Li;
    for (int i = 0; i < 6; i++) {
        float rr = tr * tr - ti * ti;
        float mm = 2.0f * tr * ti;
        tr = rr; ti = mm;
    }
    ltre[p] = tr; ltim[p] = ti;
}

// ---------------------------------------------------------------------------
// Kernel 1: B_bar planes: bbr/bbi[p*H + h] = gamma_p * (B[p,h,0] + i B[p,h,1])
// ---------------------------------------------------------------------------
__global__ void k_bbar(const float* __restrict__ B,
                       const float* __restrict__ gre, const float* __restrict__ gim,
                       float* __restrict__ bbr, float* __restrict__ bbi) {
    int t = blockIdx.x * blockDim.x + threadIdx.x;   // complex index over P*H
    if (t >= PP * HH) return;
    int p = t / HH;
    float2 b = ((const float2*)B)[t];
    float gr = gre[p], gi = gim[p];
    bbr[t] = gr * b.x - gi * b.y;
    bbi[t] = gr * b.y + gi * b.x;
}

// ---------------------------------------------------------------------------
// GEMM1: Bu[l,p] = sum_h u[l,h] * Bbar[p,h]   (two real planes, B-transposed)
// 64x64 tile, 256 threads, 4x4 register tile per thread, K-tile 16.
// ---------------------------------------------------------------------------
__global__ __launch_bounds__(256) void k_gemm1(const float* __restrict__ u,
        const float* __restrict__ bbr, const float* __restrict__ bbi,
        float* __restrict__ bur, float* __restrict__ bui) {
    __shared__ float At[64][17];
    __shared__ float Br[64][17];
    __shared__ float Bi[64][17];
    int l0 = blockIdx.y * 64;
    int p0 = blockIdx.x * 64;
    int tid = threadIdx.x;
    int tx = tid & 15, ty = tid >> 4;
    int lr = tid >> 2, lc = (tid & 3) * 4;
    float ar[4][4] = {}, ai[4][4] = {};

    for (int k0 = 0; k0 < HH; k0 += 16) {
        float4 a = *(const float4*)&u  [(size_t)(l0 + lr) * HH + k0 + lc];
        float4 r = *(const float4*)&bbr[(size_t)(p0 + lr) * HH + k0 + lc];
        float4 i4 = *(const float4*)&bbi[(size_t)(p0 + lr) * HH + k0 + lc];
        __syncthreads();
        At[lr][lc] = a.x;  At[lr][lc+1] = a.y;  At[lr][lc+2] = a.z;  At[lr][lc+3] = a.w;
        Br[lr][lc] = r.x;  Br[lr][lc+1] = r.y;  Br[lr][lc+2] = r.z;  Br[lr][lc+3] = r.w;
        Bi[lr][lc] = i4.x; Bi[lr][lc+1] = i4.y; Bi[lr][lc+2] = i4.z; Bi[lr][lc+3] = i4.w;
        __syncthreads();
        #pragma unroll
        for (int k = 0; k < 16; k++) {
            float av[4], brv[4], biv[4];
            #pragma unroll
            for (int i = 0; i < 4; i++) av[i] = At[ty * 4 + i][k];
            #pragma unroll
            for (int j = 0; j < 4; j++) { brv[j] = Br[tx * 4 + j][k]; biv[j] = Bi[tx * 4 + j][k]; }
            #pragma unroll
            for (int i = 0; i < 4; i++)
                #pragma unroll
                for (int j = 0; j < 4; j++) {
                    ar[i][j] += av[i] * brv[j];
                    ai[i][j] += av[i] * biv[j];
                }
        }
    }
    #pragma unroll
    for (int i = 0; i < 4; i++) {
        size_t row = (size_t)(l0 + ty * 4 + i) * PP + p0 + tx * 4;
        *(float4*)&bur[row] = make_float4(ar[i][0], ar[i][1], ar[i][2], ar[i][3]);
        *(float4*)&bui[row] = make_float4(ai[i][0], ai[i][1], ai[i][2], ai[i][3]);
    }
}

// ---------------------------------------------------------------------------
// Scan pass 1: per (p, chunk) local reduce with zero init -> chunk final f
// ---------------------------------------------------------------------------
__global__ void k_scan1(const float* __restrict__ bur, const float* __restrict__ bui,
                        const float* __restrict__ lbre, const float* __restrict__ lbim,
                        float* __restrict__ fr, float* __restrict__ fi) {
    int p = blockIdx.x * 256 + threadIdx.x;
    int c = blockIdx.y;
    float ar = lbre[p], ai = lbim[p];
    float xr = 0.0f, xi = 0.0f;
    int base = c * CHUNK;
    for (int j = 0; j < CHUNK; j++) {
        size_t idx = (size_t)(base + j) * PP + p;
        float br = bur[idx], bi = bui[idx];
        float nr = ar * xr - ai * xi + br;
        float ni = ar * xi + ai * xr + bi;
        xr = nr; xi = ni;
    }
    fr[c * PP + p] = xr;
    fi[c * PP + p] = xi;
}

// ---------------------------------------------------------------------------
// Scan pass 2: scan chunk carries along c (per p). carry[c] = state entering chunk c.
// ---------------------------------------------------------------------------
__global__ void k_scan2(const float* __restrict__ fr, const float* __restrict__ fi,
                        const float* __restrict__ ltre, const float* __restrict__ ltim,
                        float* __restrict__ cr, float* __restrict__ ci) {
    int p = blockIdx.x * 256 + threadIdx.x;
    float ar = ltre[p], ai = ltim[p];
    float xr = 0.0f, xi = 0.0f;
    for (int c = 0; c < NCHUNK; c++) {
        cr[c * PP + p] = xr;
        ci[c * PP + p] = xi;
        float br = fr[c * PP + p], bi = fi[c * PP + p];
        float nr = ar * xr - ai * xi + br;
        float ni = ar * xi + ai * xr + bi;
        xr = nr; xi = ni;
    }
}

// ---------------------------------------------------------------------------
// Scan pass 3: replay chunk with correct initial state, write xs in-place over Bu
// ---------------------------------------------------------------------------
__global__ void k_scan3(float* __restrict__ bur, float* __restrict__ bui,
                        const float* __restrict__ lbre, const float* __restrict__ lbim,
                        const float* __restrict__ cr, const float* __restrict__ ci) {
    int p = blockIdx.x * 256 + threadIdx.x;
    int c = blockIdx.y;
    float ar = lbre[p], ai = lbim[p];
    float xr = cr[c * PP + p], xi = ci[c * PP + p];
    int base = c * CHUNK;
    for (int j = 0; j < CHUNK; j++) {
        size_t idx = (size_t)(base + j) * PP + p;
        float br = bur[idx], bi = bui[idx];
        float nr = ar * xr - ai * xi + br;
        float ni = ar * xi + ai * xr + bi;
        xr = nr; xi = ni;
        bur[idx] = xr;
        bui[idx] = xi;
    }
}

// ---------------------------------------------------------------------------
// GEMM2: ys[l,h] = 2*sum_p (xr[l,p]*Cre[h,p] - xi[l,p]*Cim[h,p]) + u[l,h]*D[h]
// C input is (H,P,2) interleaved; de-interleave while staging to LDS.
// ---------------------------------------------------------------------------
__global__ __launch_bounds__(256) void k_gemm2(const float* __restrict__ xr,
        const float* __restrict__ xi, const float* __restrict__ C,
        const float* __restrict__ u, const float* __restrict__ D,
        float* __restrict__ out) {
    __shared__ float Ar[64][17];
    __shared__ float Ai[64][17];
    __shared__ float Cr[64][17];
    __shared__ float Ci[64][17];
    int l0 = blockIdx.y * 64;
    int h0 = blockIdx.x * 64;
    int tid = threadIdx.x;
    int tx = tid & 15, ty = tid >> 4;
    int lr = tid >> 2, q = (tid & 3);
    float acc[4][4] = {};

    for (int k0 = 0; k0 < PP; k0 += 16) {
        float4 a  = *(const float4*)&xr[(size_t)(l0 + lr) * PP + k0 + q * 4];
        float4 b  = *(const float4*)&xi[(size_t)(l0 + lr) * PP + k0 + q * 4];
        float4 c1 = *(const float4*)&C[(size_t)(h0 + lr) * (2 * PP) + 2 * k0 + q * 8];
        float4 c2 = *(const float4*)&C[(size_t)(h0 + lr) * (2 * PP) + 2 * k0 + q * 8 + 4];
        __syncthreads();
        Ar[lr][q*4]   = a.x; Ar[lr][q*4+1] = a.y; Ar[lr][q*4+2] = a.z; Ar[lr][q*4+3] = a.w;
        Ai[lr][q*4]   = b.x; Ai[lr][q*4+1] = b.y; Ai[lr][q*4+2] = b.z; Ai[lr][q*4+3] = b.w;
        Cr[lr][q*4]   = c1.x; Ci[lr][q*4]   = c1.y;
        Cr[lr][q*4+1] = c1.z; Ci[lr][q*4+1] = c1.w;
        Cr[lr][q*4+2] = c2.x; Ci[lr][q*4+2] = c2.y;
        Cr[lr][q*4+3] = c2.z; Ci[lr][q*4+3] = c2.w;
        __syncthreads();
        #pragma unroll
        for (int k = 0; k < 16; k++) {
            float arv[4], aiv[4], crv[4], civ[4];
            #pragma unroll
            for (int i = 0; i < 4; i++) { arv[i] = Ar[ty*4+i][k]; aiv[i] = Ai[ty*4+i][k]; }
            #pragma unroll
            for (int j = 0; j < 4; j++) { crv[j] = Cr[tx*4+j][k]; civ[j] = Ci[tx*4+j][k]; }
            #pragma unroll
            for (int i = 0; i < 4; i++)
                #pragma unroll
                for (int j = 0; j < 4; j++)
                    acc[i][j] += arv[i] * crv[j] - aiv[i] * civ[j];
        }
    }
    #pragma unroll
    for (int i = 0; i < 4; i++) {
        int l = l0 + ty * 4 + i;
        size_t o = (size_t)l * HH + h0 + tx * 4;
        float4 uu = *(const float4*)&u[o];
        float4 dd = *(const float4*)&D[h0 + tx * 4];
        float4 r;
        r.x = 2.0f * acc[i][0] + uu.x * dd.x;
        r.y = 2.0f * acc[i][1] + uu.y * dd.y;
        r.z = 2.0f * acc[i][2] + uu.z * dd.z;
        r.w = 2.0f * acc[i][3] + uu.w * dd.w;
        *(float4*)&out[o] = r;
    }
}

extern "C" void kernel_launch(void* const* d_in, const int* in_sizes, int n_in,
                              void* d_out, int out_size, void* d_ws, size_t ws_size,
                              hipStream_t stream) {
    const float* u       = (const float*)d_in[0];   // (L,H)
    const float* lre     = (const float*)d_in[1];   // (P,)
    const float* lim     = (const float*)d_in[2];   // (P,)
    const float* B       = (const float*)d_in[3];   // (P,H,2)
    const float* C       = (const float*)d_in[4];   // (H,P,2)
    const float* D       = (const float*)d_in[5];   // (H,)
    const float* logstep = (const float*)d_in[6];   // (P,)
    float* out = (float*)d_out;

    float* w = (float*)d_ws;
    float* gre  = w;            // 512
    float* gim  = w + 512;
    float* lbre = w + 1024;
    float* lbim = w + 1536;
    float* ltre = w + 2048;
    float* ltim = w + 2560;
    float* bbr  = w + 4096;                       // P*H
    float* bbi  = bbr + (size_t)PP * HH;          // P*H
    float* bur  = bbi + (size_t)PP * HH;          // L*P (becomes xs_re in-place)
    float* bui  = bur + (size_t)LL * PP;          // L*P (becomes xs_im in-place)
    float* fr   = bui + (size_t)LL * PP;          // NCHUNK*P
    float* fi   = fr + NCHUNK * PP;
    float* cr   = fi + NCHUNK * PP;
    float* ci   = cr + NCHUNK * PP;

    k_setup<<<1, 512, 0, stream>>>(lre, lim, logstep, gre, gim, lbre, lbim, ltre, ltim);
    k_bbar<<<(PP * HH) / 256, 256, 0, stream>>>(B, gre, gim, bbr, bbi);
    k_gemm1<<<dim3(PP / 64, LL / 64), 256, 0, stream>>>(u, bbr, bbi, bur, bui);
    k_scan1<<<dim3(PP / 256, NCHUNK), 256, 0, stream>>>(bur, bui, lbre, lbim, fr, fi);
    k_scan2<<<PP / 256, 256, 0, stream>>>(fr, fi, ltre, ltim, cr, ci);
    k_scan3<<<dim3(PP / 256, NCHUNK), 256, 0, stream>>>(bur, bui, lbre, lbim, cr, ci);
    k_gemm2<<<dim3(HH / 64, LL / 64), 256, 0, stream>>>(bur, bui, C, u, D, out);
}

// Round 2
// 301.573 us; speedup vs baseline: 5.3918x; 5.3918x over previous
//
#include <hip/hip_runtime.h>
#include <math.h>

#define LL 16384
#define HH 1024
#define PP 512
#define NP2 1024        // 2*PP (re|im concatenated)
#define CHUNK 64
#define NCHUNK 256
#define BM 128
#define BN 128
#define BK 32

typedef unsigned short u16;
typedef __attribute__((ext_vector_type(8))) short bf16x8;   // 8 bf16 = 4 VGPRs
typedef __attribute__((ext_vector_type(4))) float f32x4;

__device__ __forceinline__ u16 f2bf(float f) {
    unsigned u = __float_as_uint(f);
    unsigned r = 0x7fffu + ((u >> 16) & 1u);   // RNE
    return (u16)((u + r) >> 16);
}

__device__ __forceinline__ void gload_lds16(const void* g, void* l) {
    __builtin_amdgcn_global_load_lds(
        (const __attribute__((address_space(1))) unsigned int*)g,
        (__attribute__((address_space(3))) unsigned int*)l, 16, 0, 0);
}

// ---------------------------------------------------------------------------
// Discretization constants per p.
// ---------------------------------------------------------------------------
__global__ void k_setup(const float* __restrict__ lre, const float* __restrict__ lim,
                        const float* __restrict__ logstep,
                        float* __restrict__ gre, float* __restrict__ gim,
                        float* __restrict__ lbre, float* __restrict__ lbim,
                        float* __restrict__ ltre, float* __restrict__ ltim) {
    int p = threadIdx.x;
    if (p >= PP) return;
    float dt = expf(logstep[p]);           // STEP_RESCALE = 1
    float ar = lre[p], ai = lim[p];
    float e = expf(ar * dt);
    float s, c;
    sincosf(ai * dt, &s, &c);
    float Lr = e * c, Li = e * s;          // Lambda_bar
    lbre[p] = Lr; lbim[p] = Li;
    float nr = Lr - 1.0f, ni = Li;
    float den = ar * ar + ai * ai;
    gre[p] = (nr * ar + ni * ai) / den;    // gamma = (Lambda_bar-1)/Lambda
    gim[p] = (ni * ar - nr * ai) / den;
    float tr = Lr, ti = Li;                // Lambda_bar^64 via 6 squarings
    for (int i = 0; i < 6; i++) {
        float rr = tr * tr - ti * ti;
        float mm = 2.0f * tr * ti;
        tr = rr; ti = mm;
    }
    ltre[p] = tr; ltim[p] = ti;
}

// ---------------------------------------------------------------------------
// B_bar -> bf16, rows [0..P) = re plane, rows [P..2P) = im plane. (2P x H)
// ---------------------------------------------------------------------------
__global__ void k_bbar(const float* __restrict__ B,
                       const float* __restrict__ gre, const float* __restrict__ gim,
                       u16* __restrict__ bb) {
    int t = blockIdx.x * 256 + threadIdx.x;   // over P*H
    int p = t >> 10;
    float2 b = ((const float2*)B)[t];
    float gr = gre[p], gi = gim[p];
    bb[t] = f2bf(gr * b.x - gi * b.y);
    bb[(size_t)PP * HH + t] = f2bf(gr * b.y + gi * b.x);
}

// ---------------------------------------------------------------------------
// C -> bf16, cp[h][0..P) = C_re, cp[h][P..2P) = -C_im.  (H x 2P)
// ---------------------------------------------------------------------------
__global__ void k_cprep(const float* __restrict__ C, u16* __restrict__ cp) {
    int t = blockIdx.x * 256 + threadIdx.x;   // over H*P
    int h = t >> 9, p = t & 511;
    float2 c = ((const float2*)C)[t];
    cp[(size_t)h * NP2 + p] = f2bf(c.x);
    cp[(size_t)h * NP2 + PP + p] = f2bf(-c.y);
}

// ---------------------------------------------------------------------------
// u fp32 -> bf16 (L x H), 4 elements/thread.
// ---------------------------------------------------------------------------
__global__ void k_cvt(const float* __restrict__ s, u16* __restrict__ d) {
    size_t i = ((size_t)blockIdx.x * 256 + threadIdx.x) * 4;
    float4 v = *(const float4*)&s[i];
    unsigned lo = (unsigned)f2bf(v.x) | ((unsigned)f2bf(v.y) << 16);
    unsigned hi = (unsigned)f2bf(v.z) | ((unsigned)f2bf(v.w) << 16);
    *(uint2*)&d[i] = make_uint2(lo, hi);
}

// ---------------------------------------------------------------------------
// bf16 MFMA GEMM_BT: C[M x N] = A[M x K] * Bt[N x K]^T
// 128x128 tile, BK=32, 256 threads (4 waves, 2x2), global_load_lds width=16.
// FUSE=0: store fp32.  FUSE=1: out = 2*acc + uin*Din[col].
// ---------------------------------------------------------------------------
template<int FUSE>
__global__ __launch_bounds__(256) void k_gemm(
        const u16* __restrict__ A, const u16* __restrict__ Bt,
        float* __restrict__ Cout, const int K,
        const float* __restrict__ uin, const float* __restrict__ Din) {
    __shared__ u16 lA[BM * BK];   // 8 KB, row-major [row][32], no padding
    __shared__ u16 lB[BN * BK];   // 8 KB
    const int t = threadIdx.x;
    const int m0 = blockIdx.y * BM;
    const int n0 = blockIdx.x * BN;
    const int N = gridDim.x * BN;
    const int lane = t & 63, wid = t >> 6;
    const int wm = (wid >> 1) * 64, wn = (wid & 1) * 64;
    const int frow = lane & 15, quad = lane >> 4;

    f32x4 acc[4][4];
    #pragma unroll
    for (int i = 0; i < 4; i++)
        #pragma unroll
        for (int j = 0; j < 4; j++) acc[i][j] = (f32x4){0.f, 0.f, 0.f, 0.f};

    // staging: thread t loads 16B; row = t>>2 (and +64), col-seg = (t&3)*8
    const int sr = t >> 2, sc = (t & 3) * 8;
    const u16* gA = A + (size_t)(m0 + sr) * K + sc;
    const u16* gB = Bt + (size_t)(n0 + sr) * K + sc;
    u16* dA = &lA[sr * BK + sc];
    u16* dB = &lB[sr * BK + sc];

    for (int k0 = 0; k0 < K; k0 += BK) {
        __syncthreads();
        gload_lds16(gA + k0, dA);
        gload_lds16(gA + (size_t)64 * K + k0, dA + 64 * BK);
        gload_lds16(gB + k0, dB);
        gload_lds16(gB + (size_t)64 * K + k0, dB + 64 * BK);
        __syncthreads();
        bf16x8 av[4], bv[4];
        #pragma unroll
        for (int i = 0; i < 4; i++)
            av[i] = *(const bf16x8*)&lA[(wm + i * 16 + frow) * BK + quad * 8];
        #pragma unroll
        for (int j = 0; j < 4; j++)
            bv[j] = *(const bf16x8*)&lB[(wn + j * 16 + frow) * BK + quad * 8];
        #pragma unroll
        for (int i = 0; i < 4; i++)
            #pragma unroll
            for (int j = 0; j < 4; j++)
                acc[i][j] = __builtin_amdgcn_mfma_f32_16x16x32_bf16(
                    av[i], bv[j], acc[i][j], 0, 0, 0);
    }

    #pragma unroll
    for (int i = 0; i < 4; i++) {
        const int row = m0 + wm + i * 16 + quad * 4;   // + r
        #pragma unroll
        for (int j = 0; j < 4; j++) {
            const int col = n0 + wn + j * 16 + frow;
            f32x4 v = acc[i][j];
            if (FUSE) {
                const float dv = Din[col];
                #pragma unroll
                for (int r = 0; r < 4; r++) {
                    const size_t o = (size_t)(row + r) * N + col;
                    Cout[o] = 2.0f * v[r] + uin[o] * dv;
                }
            } else {
                #pragma unroll
                for (int r = 0; r < 4; r++)
                    Cout[(size_t)(row + r) * N + col] = v[r];
            }
        }
    }
}

// ---------------------------------------------------------------------------
// Scan pass 1: per (p, chunk) local reduce, zero init -> chunk final.
// Bu layout: (L x 2P) fp32, re at col p, im at col 512+p.
// ---------------------------------------------------------------------------
__global__ void k_scan1(const float* __restrict__ bu,
                        const float* __restrict__ lbre, const float* __restrict__ lbim,
                        float* __restrict__ fr, float* __restrict__ fi) {
    int p = blockIdx.x * 256 + threadIdx.x;
    int c = blockIdx.y;
    float ar = lbre[p], ai = lbim[p];
    float xr = 0.f, xi = 0.f;
    const float* b = bu + (size_t)c * CHUNK * NP2 + p;
    for (int j = 0; j < CHUNK; j++) {
        float br = b[0], bi = b[PP];
        float nr = ar * xr - ai * xi + br;
        float ni = ar * xi + ai * xr + bi;
        xr = nr; xi = ni;
        b += NP2;
    }
    fr[c * PP + p] = xr;
    fi[c * PP + p] = xi;
}

// ---------------------------------------------------------------------------
// Scan pass 2: serial scan of chunk carries (256 chunks) per p.
// ---------------------------------------------------------------------------
__global__ void k_scan2(const float* __restrict__ fr, const float* __restrict__ fi,
                        const float* __restrict__ ltre, const float* __restrict__ ltim,
                        float* __restrict__ cr, float* __restrict__ ci) {
    int p = blockIdx.x * 256 + threadIdx.x;
    float ar = ltre[p], ai = ltim[p];
    float xr = 0.f, xi = 0.f;
    for (int c = 0; c < NCHUNK; c++) {
        cr[c * PP + p] = xr;
        ci[c * PP + p] = xi;
        float br = fr[c * PP + p], bi = fi[c * PP + p];
        float nr = ar * xr - ai * xi + br;
        float ni = ar * xi + ai * xr + bi;
        xr = nr; xi = ni;
    }
}

// ---------------------------------------------------------------------------
// Scan pass 3: replay with correct carry; emit xs as bf16 (L x 2P, re|im).
// ---------------------------------------------------------------------------
__global__ void k_scan3(const float* __restrict__ bu,
                        const float* __restrict__ lbre, const float* __restrict__ lbim,
                        const float* __restrict__ cr, const float* __restrict__ ci,
                        u16* __restrict__ xsb) {
    int p = blockIdx.x * 256 + threadIdx.x;
    int c = blockIdx.y;
    float ar = lbre[p], ai = lbim[p];
    float xr = cr[c * PP + p], xi = ci[c * PP + p];
    const float* b = bu + (size_t)c * CHUNK * NP2 + p;
    u16* o = xsb + (size_t)c * CHUNK * NP2 + p;
    for (int j = 0; j < CHUNK; j++) {
        float br = b[0], bi = b[PP];
        float nr = ar * xr - ai * xi + br;
        float ni = ar * xi + ai * xr + bi;
        xr = nr; xi = ni;
        o[0] = f2bf(xr);
        o[PP] = f2bf(xi);
        b += NP2; o += NP2;
    }
}

extern "C" void kernel_launch(void* const* d_in, const int* in_sizes, int n_in,
                              void* d_out, int out_size, void* d_ws, size_t ws_size,
                              hipStream_t stream) {
    const float* u       = (const float*)d_in[0];   // (L,H)
    const float* lre     = (const float*)d_in[1];   // (P,)
    const float* lim     = (const float*)d_in[2];   // (P,)
    const float* B       = (const float*)d_in[3];   // (P,H,2)
    const float* C       = (const float*)d_in[4];   // (H,P,2)
    const float* D       = (const float*)d_in[5];   // (H,)
    const float* logstep = (const float*)d_in[6];   // (P,)
    float* out = (float*)d_out;

    float* w = (float*)d_ws;
    float* gre  = w;
    float* gim  = w + 512;
    float* lbre = w + 1024;
    float* lbim = w + 1536;
    float* ltre = w + 2048;
    float* ltim = w + 2560;
    float* fr   = w + 4096;                       // NCHUNK*PP each
    float* fi   = fr + NCHUNK * PP;
    float* cr   = fi + NCHUNK * PP;
    float* ci   = cr + NCHUNK * PP;
    float* bu   = w + (1 << 20);                  // L*2P fp32 = 64 MB
    u16*   ub   = (u16*)(bu + (size_t)LL * NP2);  // L*H bf16 = 32 MB (reused as xsb)
    u16*   bb   = ub + (size_t)LL * HH;           // 2P*H bf16 = 2 MB
    u16*   cp   = bb + (size_t)NP2 * HH;          // H*2P bf16 = 2 MB
    u16*   xsb  = ub;                             // alias: ub dead after GEMM1

    k_setup<<<1, 512, 0, stream>>>(lre, lim, logstep, gre, gim, lbre, lbim, ltre, ltim);
    k_bbar<<<(PP * HH) / 256, 256, 0, stream>>>(B, gre, gim, bb);
    k_cprep<<<(HH * PP) / 256, 256, 0, stream>>>(C, cp);
    k_cvt<<<(LL * HH) / 1024, 256, 0, stream>>>(u, ub);
    k_gemm<0><<<dim3(NP2 / BN, LL / BM), 256, 0, stream>>>(ub, bb, bu, HH, nullptr, nullptr);
    k_scan1<<<dim3(PP / 256, NCHUNK), 256, 0, stream>>>(bu, lbre, lbim, fr, fi);
    k_scan2<<<PP / 256, 256, 0, stream>>>(fr, fi, ltre, ltim, cr, ci);
    k_scan3<<<dim3(PP / 256, NCHUNK), 256, 0, stream>>>(bu, lbre, lbim, cr, ci, xsb);
    k_gemm<1><<<dim3(HH / BN, LL / BM), 256, 0, stream>>>(xsb, cp, out, NP2, u, D);
}

// Round 3
// 277.625 us; speedup vs baseline: 5.8569x; 1.0863x over previous
//
#include <hip/hip_runtime.h>
#include <math.h>

#define LL 16384
#define HH 1024
#define PP 512
#define NP2 1024        // 2*PP (re|im concatenated)
#define CHUNK 64
#define NCHUNK 256
#define BM 128
#define BN 128
#define BK 32

typedef unsigned short u16;
typedef __attribute__((ext_vector_type(8))) short bf16x8;   // 8 bf16 = 4 VGPRs
typedef __attribute__((ext_vector_type(4))) float f32x4;

__device__ __forceinline__ u16 f2bf(float f) {
    unsigned u = __float_as_uint(f);
    unsigned r = 0x7fffu + ((u >> 16) & 1u);   // RNE
    return (u16)((u + r) >> 16);
}
__device__ __forceinline__ float bf2f(u16 x) {
    return __uint_as_float(((unsigned)x) << 16);
}

__device__ __forceinline__ void gload_lds16(const void* g, void* l) {
    __builtin_amdgcn_global_load_lds(
        (const __attribute__((address_space(1))) unsigned int*)g,
        (__attribute__((address_space(3))) unsigned int*)l, 16, 0, 0);
}

// ---------------------------------------------------------------------------
// Discretization constants per p.
// ---------------------------------------------------------------------------
__global__ void k_setup(const float* __restrict__ lre, const float* __restrict__ lim,
                        const float* __restrict__ logstep,
                        float* __restrict__ gre, float* __restrict__ gim,
                        float* __restrict__ lbre, float* __restrict__ lbim,
                        float* __restrict__ ltre, float* __restrict__ ltim) {
    int p = threadIdx.x;
    if (p >= PP) return;
    float dt = expf(logstep[p]);           // STEP_RESCALE = 1
    float ar = lre[p], ai = lim[p];
    float e = expf(ar * dt);
    float s, c;
    sincosf(ai * dt, &s, &c);
    float Lr = e * c, Li = e * s;          // Lambda_bar
    lbre[p] = Lr; lbim[p] = Li;
    float nr = Lr - 1.0f, ni = Li;
    float den = ar * ar + ai * ai;
    gre[p] = (nr * ar + ni * ai) / den;    // gamma = (Lambda_bar-1)/Lambda
    gim[p] = (ni * ar - nr * ai) / den;
    float tr = Lr, ti = Li;                // Lambda_bar^64 via 6 squarings
    for (int i = 0; i < 6; i++) {
        float rr = tr * tr - ti * ti;
        float mm = 2.0f * tr * ti;
        tr = rr; ti = mm;
    }
    ltre[p] = tr; ltim[p] = ti;
}

// ---------------------------------------------------------------------------
// B_bar -> bf16, rows [0..P) = re plane, rows [P..2P) = im plane. (2P x H)
// ---------------------------------------------------------------------------
__global__ void k_bbar(const float* __restrict__ B,
                       const float* __restrict__ gre, const float* __restrict__ gim,
                       u16* __restrict__ bb) {
    int t = blockIdx.x * 256 + threadIdx.x;   // over P*H
    int p = t >> 10;
    float2 b = ((const float2*)B)[t];
    float gr = gre[p], gi = gim[p];
    bb[t] = f2bf(gr * b.x - gi * b.y);
    bb[(size_t)PP * HH + t] = f2bf(gr * b.y + gi * b.x);
}

// ---------------------------------------------------------------------------
// C -> bf16, cp[h][0..P) = C_re, cp[h][P..2P) = -C_im.  (H x 2P)
// ---------------------------------------------------------------------------
__global__ void k_cprep(const float* __restrict__ C, u16* __restrict__ cp) {
    int t = blockIdx.x * 256 + threadIdx.x;   // over H*P
    int h = t >> 9, p = t & 511;
    float2 c = ((const float2*)C)[t];
    cp[(size_t)h * NP2 + p] = f2bf(c.x);
    cp[(size_t)h * NP2 + PP + p] = f2bf(-c.y);
}

// ---------------------------------------------------------------------------
// u fp32 -> bf16 (L x H), 4 elements/thread.
// ---------------------------------------------------------------------------
__global__ void k_cvt(const float* __restrict__ s, u16* __restrict__ d) {
    size_t i = ((size_t)blockIdx.x * 256 + threadIdx.x) * 4;
    float4 v = *(const float4*)&s[i];
    unsigned lo = (unsigned)f2bf(v.x) | ((unsigned)f2bf(v.y) << 16);
    unsigned hi = (unsigned)f2bf(v.z) | ((unsigned)f2bf(v.w) << 16);
    *(uint2*)&d[i] = make_uint2(lo, hi);
}

// ---------------------------------------------------------------------------
// bf16 MFMA GEMM_BT: C[M x N] = A[M x K] * Bt[N x K]^T,  N = 1024 (8 tiles).
// 128x128 tile, BK=32, 256 threads (4 waves, 2x2), global_load_lds width=16.
// 1-D grid with XCD-aware swizzle: xcd = b&7 owns M-tile band [xcd*16,xcd*16+16),
// consecutive per-XCD blocks share an A row-tile -> A fetched once per device.
// FUSE=0: store bf16.  FUSE=1: out = 2*acc + bf2f(ubf)*Din[col], fp32.
// ---------------------------------------------------------------------------
template<int FUSE>
__global__ __launch_bounds__(256) void k_gemm(
        const u16* __restrict__ A, const u16* __restrict__ Bt,
        void* __restrict__ outp, const int K,
        const u16* __restrict__ ubf, const float* __restrict__ Din) {
    __shared__ u16 lA[BM * BK];   // 8 KB, row-major [row][32], no padding
    __shared__ u16 lB[BN * BK];   // 8 KB
    const int b = blockIdx.x;
    const int xcd = b & 7, s = b >> 3;
    const int m0 = (xcd * 16 + (s >> 3)) * BM;
    const int n0 = (s & 7) * BN;
    const int N = 8 * BN;
    const int t = threadIdx.x;
    const int lane = t & 63, wid = t >> 6;
    const int wm = (wid >> 1) * 64, wn = (wid & 1) * 64;
    const int frow = lane & 15, quad = lane >> 4;

    f32x4 acc[4][4];
    #pragma unroll
    for (int i = 0; i < 4; i++)
        #pragma unroll
        for (int j = 0; j < 4; j++) acc[i][j] = (f32x4){0.f, 0.f, 0.f, 0.f};

    // staging: thread t loads 16B; row = t>>2 (and +64), col-seg = (t&3)*8
    const int sr = t >> 2, sc = (t & 3) * 8;
    const u16* gA = A + (size_t)(m0 + sr) * K + sc;
    const u16* gB = Bt + (size_t)(n0 + sr) * K + sc;
    u16* dA = &lA[sr * BK + sc];
    u16* dB = &lB[sr * BK + sc];

    for (int k0 = 0; k0 < K; k0 += BK) {
        __syncthreads();
        gload_lds16(gA + k0, dA);
        gload_lds16(gA + (size_t)64 * K + k0, dA + 64 * BK);
        gload_lds16(gB + k0, dB);
        gload_lds16(gB + (size_t)64 * K + k0, dB + 64 * BK);
        __syncthreads();
        bf16x8 av[4], bv[4];
        #pragma unroll
        for (int i = 0; i < 4; i++)
            av[i] = *(const bf16x8*)&lA[(wm + i * 16 + frow) * BK + quad * 8];
        #pragma unroll
        for (int j = 0; j < 4; j++)
            bv[j] = *(const bf16x8*)&lB[(wn + j * 16 + frow) * BK + quad * 8];
        #pragma unroll
        for (int i = 0; i < 4; i++)
            #pragma unroll
            for (int j = 0; j < 4; j++)
                acc[i][j] = __builtin_amdgcn_mfma_f32_16x16x32_bf16(
                    av[i], bv[j], acc[i][j], 0, 0, 0);
    }

    #pragma unroll
    for (int i = 0; i < 4; i++) {
        const int row = m0 + wm + i * 16 + quad * 4;   // + r
        #pragma unroll
        for (int j = 0; j < 4; j++) {
            const int col = n0 + wn + j * 16 + frow;
            f32x4 v = acc[i][j];
            if (FUSE) {
                float* Cout = (float*)outp;
                const float dv = Din[col];
                #pragma unroll
                for (int r = 0; r < 4; r++) {
                    const size_t o = (size_t)(row + r) * N + col;
                    Cout[o] = 2.0f * v[r] + bf2f(ubf[o]) * dv;
                }
            } else {
                u16* Cb = (u16*)outp;
                #pragma unroll
                for (int r = 0; r < 4; r++)
                    Cb[(size_t)(row + r) * N + col] = f2bf(v[r]);
            }
        }
    }
}

// ---------------------------------------------------------------------------
// Scan pass 1: per (p, chunk) local reduce, zero init -> chunk final.
// Bu layout: (L x 2P) bf16, re at col p, im at col 512+p. State fp32.
// ---------------------------------------------------------------------------
__global__ void k_scan1(const u16* __restrict__ bu,
                        const float* __restrict__ lbre, const float* __restrict__ lbim,
                        float* __restrict__ fr, float* __restrict__ fi) {
    int p = blockIdx.x * 256 + threadIdx.x;
    int c = blockIdx.y;
    float ar = lbre[p], ai = lbim[p];
    float xr = 0.f, xi = 0.f;
    const u16* b = bu + (size_t)c * CHUNK * NP2 + p;
    for (int j = 0; j < CHUNK; j++) {
        float br = bf2f(b[0]), bi = bf2f(b[PP]);
        float nr = ar * xr - ai * xi + br;
        float ni = ar * xi + ai * xr + bi;
        xr = nr; xi = ni;
        b += NP2;
    }
    fr[c * PP + p] = xr;
    fi[c * PP + p] = xi;
}

// ---------------------------------------------------------------------------
// Scan pass 2: serial scan of chunk carries (256 chunks) per p.
// ---------------------------------------------------------------------------
__global__ void k_scan2(const float* __restrict__ fr, const float* __restrict__ fi,
                        const float* __restrict__ ltre, const float* __restrict__ ltim,
                        float* __restrict__ cr, float* __restrict__ ci) {
    int p = blockIdx.x * 256 + threadIdx.x;
    float ar = ltre[p], ai = ltim[p];
    float xr = 0.f, xi = 0.f;
    for (int c = 0; c < NCHUNK; c++) {
        cr[c * PP + p] = xr;
        ci[c * PP + p] = xi;
        float br = fr[c * PP + p], bi = fi[c * PP + p];
        float nr = ar * xr - ai * xi + br;
        float ni = ar * xi + ai * xr + bi;
        xr = nr; xi = ni;
    }
}

// ---------------------------------------------------------------------------
// Scan pass 3: replay with correct carry; overwrite Bu with xs (bf16, in-place).
// Same thread reads element then writes it -> in-place safe.
// ---------------------------------------------------------------------------
__global__ void k_scan3(u16* __restrict__ bu,
                        const float* __restrict__ lbre, const float* __restrict__ lbim,
                        const float* __restrict__ cr, const float* __restrict__ ci) {
    int p = blockIdx.x * 256 + threadIdx.x;
    int c = blockIdx.y;
    float ar = lbre[p], ai = lbim[p];
    float xr = cr[c * PP + p], xi = ci[c * PP + p];
    u16* b = bu + (size_t)c * CHUNK * NP2 + p;
    for (int j = 0; j < CHUNK; j++) {
        float br = bf2f(b[0]), bi = bf2f(b[PP]);
        float nr = ar * xr - ai * xi + br;
        float ni = ar * xi + ai * xr + bi;
        xr = nr; xi = ni;
        b[0] = f2bf(xr);
        b[PP] = f2bf(xi);
        b += NP2;
    }
}

extern "C" void kernel_launch(void* const* d_in, const int* in_sizes, int n_in,
                              void* d_out, int out_size, void* d_ws, size_t ws_size,
                              hipStream_t stream) {
    const float* u       = (const float*)d_in[0];   // (L,H)
    const float* lre     = (const float*)d_in[1];   // (P,)
    const float* lim     = (const float*)d_in[2];   // (P,)
    const float* B       = (const float*)d_in[3];   // (P,H,2)
    const float* C       = (const float*)d_in[4];   // (H,P,2)
    const float* D       = (const float*)d_in[5];   // (H,)
    const float* logstep = (const float*)d_in[6];   // (P,)
    float* out = (float*)d_out;

    float* w = (float*)d_ws;
    float* gre  = w;
    float* gim  = w + 512;
    float* lbre = w + 1024;
    float* lbim = w + 1536;
    float* ltre = w + 2048;
    float* ltim = w + 2560;
    float* fr   = w + 4096;                       // NCHUNK*PP each
    float* fi   = fr + NCHUNK * PP;
    float* cr   = fi + NCHUNK * PP;
    float* ci   = cr + NCHUNK * PP;
    u16*   bub  = (u16*)(w + (1 << 20));          // L*2P bf16 = 32 MB (Bu -> xs in-place)
    u16*   ub   = bub + (size_t)LL * NP2;         // L*H bf16 = 32 MB
    u16*   bb   = ub + (size_t)LL * HH;           // 2P*H bf16 = 2 MB
    u16*   cp   = bb + (size_t)NP2 * HH;          // H*2P bf16 = 2 MB

    k_setup<<<1, 512, 0, stream>>>(lre, lim, logstep, gre, gim, lbre, lbim, ltre, ltim);
    k_bbar<<<(PP * HH) / 256, 256, 0, stream>>>(B, gre, gim, bb);
    k_cprep<<<(HH * PP) / 256, 256, 0, stream>>>(C, cp);
    k_cvt<<<(LL * HH) / 1024, 256, 0, stream>>>(u, ub);
    k_gemm<0><<<(NP2 / BN) * (LL / BM), 256, 0, stream>>>(ub, bb, bub, HH, nullptr, nullptr);
    k_scan1<<<dim3(PP / 256, NCHUNK), 256, 0, stream>>>(bub, lbre, lbim, fr, fi);
    k_scan2<<<PP / 256, 256, 0, stream>>>(fr, fi, ltre, ltim, cr, ci);
    k_scan3<<<dim3(PP / 256, NCHUNK), 256, 0, stream>>>(bub, lbre, lbim, cr, ci);
    k_gemm<1><<<(HH / BN) * (LL / BM), 256, 0, stream>>>(bub, cp, out, NP2, ub, D);
}

// Round 4
// 269.425 us; speedup vs baseline: 6.0352x; 1.0304x over previous
//
#include <hip/hip_runtime.h>
#include <math.h>

#define LL 16384
#define HH 1024
#define PP 512
#define NP2 1024        // 2*PP (re|im concatenated)
#define CHUNK 64
#define NCHUNK 256
#define BM 128
#define BN 128
#define BK 32

typedef unsigned short u16;
typedef __attribute__((ext_vector_type(8))) short bf16x8;   // 8 bf16 = 4 VGPRs
typedef __attribute__((ext_vector_type(4))) float f32x4;

__device__ __forceinline__ u16 f2bf(float f) {
    unsigned u = __float_as_uint(f);
    unsigned r = 0x7fffu + ((u >> 16) & 1u);   // RNE
    return (u16)((u + r) >> 16);
}
__device__ __forceinline__ float bf2f(u16 x) {
    return __uint_as_float(((unsigned)x) << 16);
}

__device__ __forceinline__ void gload_lds16(const void* g, void* l) {
    __builtin_amdgcn_global_load_lds(
        (const __attribute__((address_space(1))) unsigned int*)g,
        (__attribute__((address_space(3))) unsigned int*)l, 16, 0, 0);
}

// ---------------------------------------------------------------------------
// Discretization constants per p.
// ---------------------------------------------------------------------------
__global__ void k_setup(const float* __restrict__ lre, const float* __restrict__ lim,
                        const float* __restrict__ logstep,
                        float* __restrict__ gre, float* __restrict__ gim,
                        float* __restrict__ lbre, float* __restrict__ lbim,
                        float* __restrict__ ltre, float* __restrict__ ltim) {
    int p = threadIdx.x;
    if (p >= PP) return;
    float dt = expf(logstep[p]);           // STEP_RESCALE = 1
    float ar = lre[p], ai = lim[p];
    float e = expf(ar * dt);
    float s, c;
    sincosf(ai * dt, &s, &c);
    float Lr = e * c, Li = e * s;          // Lambda_bar
    lbre[p] = Lr; lbim[p] = Li;
    float nr = Lr - 1.0f, ni = Li;
    float den = ar * ar + ai * ai;
    gre[p] = (nr * ar + ni * ai) / den;    // gamma = (Lambda_bar-1)/Lambda
    gim[p] = (ni * ar - nr * ai) / den;
    float tr = Lr, ti = Li;                // Lambda_bar^64 via 6 squarings
    for (int i = 0; i < 6; i++) {
        float rr = tr * tr - ti * ti;
        float mm = 2.0f * tr * ti;
        tr = rr; ti = mm;
    }
    ltre[p] = tr; ltim[p] = ti;
}

// ---------------------------------------------------------------------------
// B_bar -> bf16, rows [0..P) = re plane, rows [P..2P) = im plane. (2P x H)
// ---------------------------------------------------------------------------
__global__ void k_bbar(const float* __restrict__ B,
                       const float* __restrict__ gre, const float* __restrict__ gim,
                       u16* __restrict__ bb) {
    int t = blockIdx.x * 256 + threadIdx.x;   // over P*H
    int p = t >> 10;
    float2 b = ((const float2*)B)[t];
    float gr = gre[p], gi = gim[p];
    bb[t] = f2bf(gr * b.x - gi * b.y);
    bb[(size_t)PP * HH + t] = f2bf(gr * b.y + gi * b.x);
}

// ---------------------------------------------------------------------------
// C -> bf16, cp[h][0..P) = C_re, cp[h][P..2P) = -C_im.  (H x 2P)
// ---------------------------------------------------------------------------
__global__ void k_cprep(const float* __restrict__ C, u16* __restrict__ cp) {
    int t = blockIdx.x * 256 + threadIdx.x;   // over H*P
    int h = t >> 9, p = t & 511;
    float2 c = ((const float2*)C)[t];
    cp[(size_t)h * NP2 + p] = f2bf(c.x);
    cp[(size_t)h * NP2 + PP + p] = f2bf(-c.y);
}

// ---------------------------------------------------------------------------
// u fp32 -> bf16 (L x H), 4 elements/thread.
// ---------------------------------------------------------------------------
__global__ void k_cvt(const float* __restrict__ s, u16* __restrict__ d) {
    size_t i = ((size_t)blockIdx.x * 256 + threadIdx.x) * 4;
    float4 v = *(const float4*)&s[i];
    unsigned lo = (unsigned)f2bf(v.x) | ((unsigned)f2bf(v.y) << 16);
    unsigned hi = (unsigned)f2bf(v.z) | ((unsigned)f2bf(v.w) << 16);
    *(uint2*)&d[i] = make_uint2(lo, hi);
}

// ---------------------------------------------------------------------------
// bf16 MFMA GEMM_BT: C[M x N] = A[M x K] * Bt[N x K]^T,  N = 1024 (8 tiles).
// 128x128 tile, BK=32, 256 threads (4 waves, 2x2), global_load_lds width=16.
// XCD-aware swizzle: xcd = b&7 owns M-tile band -> A fetched once per device.
// FUSE=0: store bf16.  FUSE=1: out = 2*acc + bf2f(ubf)*Din[col], fp32.
// ---------------------------------------------------------------------------
template<int FUSE>
__global__ __launch_bounds__(256) void k_gemm(
        const u16* __restrict__ A, const u16* __restrict__ Bt,
        void* __restrict__ outp, const int K,
        const u16* __restrict__ ubf, const float* __restrict__ Din) {
    __shared__ u16 lA[BM * BK];   // 8 KB, row-major [row][32], no padding
    __shared__ u16 lB[BN * BK];   // 8 KB
    const int b = blockIdx.x;
    const int xcd = b & 7, s = b >> 3;
    const int m0 = (xcd * 16 + (s >> 3)) * BM;
    const int n0 = (s & 7) * BN;
    const int N = 8 * BN;
    const int t = threadIdx.x;
    const int lane = t & 63, wid = t >> 6;
    const int wm = (wid >> 1) * 64, wn = (wid & 1) * 64;
    const int frow = lane & 15, quad = lane >> 4;

    f32x4 acc[4][4];
    #pragma unroll
    for (int i = 0; i < 4; i++)
        #pragma unroll
        for (int j = 0; j < 4; j++) acc[i][j] = (f32x4){0.f, 0.f, 0.f, 0.f};

    const int sr = t >> 2, sc = (t & 3) * 8;
    const u16* gA = A + (size_t)(m0 + sr) * K + sc;
    const u16* gB = Bt + (size_t)(n0 + sr) * K + sc;
    u16* dA = &lA[sr * BK + sc];
    u16* dB = &lB[sr * BK + sc];

    for (int k0 = 0; k0 < K; k0 += BK) {
        __syncthreads();
        gload_lds16(gA + k0, dA);
        gload_lds16(gA + (size_t)64 * K + k0, dA + 64 * BK);
        gload_lds16(gB + k0, dB);
        gload_lds16(gB + (size_t)64 * K + k0, dB + 64 * BK);
        __syncthreads();
        bf16x8 av[4], bv[4];
        #pragma unroll
        for (int i = 0; i < 4; i++)
            av[i] = *(const bf16x8*)&lA[(wm + i * 16 + frow) * BK + quad * 8];
        #pragma unroll
        for (int j = 0; j < 4; j++)
            bv[j] = *(const bf16x8*)&lB[(wn + j * 16 + frow) * BK + quad * 8];
        #pragma unroll
        for (int i = 0; i < 4; i++)
            #pragma unroll
            for (int j = 0; j < 4; j++)
                acc[i][j] = __builtin_amdgcn_mfma_f32_16x16x32_bf16(
                    av[i], bv[j], acc[i][j], 0, 0, 0);
    }

    #pragma unroll
    for (int i = 0; i < 4; i++) {
        const int row = m0 + wm + i * 16 + quad * 4;   // + r
        #pragma unroll
        for (int j = 0; j < 4; j++) {
            const int col = n0 + wn + j * 16 + frow;
            f32x4 v = acc[i][j];
            if (FUSE) {
                float* Cout = (float*)outp;
                const float dv = Din[col];
                #pragma unroll
                for (int r = 0; r < 4; r++) {
                    const size_t o = (size_t)(row + r) * N + col;
                    Cout[o] = 2.0f * v[r] + bf2f(ubf[o]) * dv;
                }
            } else {
                u16* Cb = (u16*)outp;
                #pragma unroll
                for (int r = 0; r < 4; r++)
                    Cb[(size_t)(row + r) * N + col] = f2bf(v[r]);
            }
        }
    }
}

// ---------------------------------------------------------------------------
// Scan pass 1: per (p, chunk) local reduce, zero init -> chunk final.
// Bu layout: (L x 2P) bf16, re at col p, im at col 512+p. State fp32.
// ---------------------------------------------------------------------------
__global__ void k_scan1(const u16* __restrict__ bu,
                        const float* __restrict__ lbre, const float* __restrict__ lbim,
                        float* __restrict__ fr, float* __restrict__ fi) {
    int p = blockIdx.x * 256 + threadIdx.x;
    int c = blockIdx.y;
    float ar = lbre[p], ai = lbim[p];
    float xr = 0.f, xi = 0.f;
    const u16* b = bu + (size_t)c * CHUNK * NP2 + p;
    for (int j = 0; j < CHUNK; j++) {
        float br = bf2f(b[0]), bi = bf2f(b[PP]);
        float nr = ar * xr - ai * xi + br;
        float ni = ar * xi + ai * xr + bi;
        xr = nr; xi = ni;
        b += NP2;
    }
    fr[c * PP + p] = xr;
    fi[c * PP + p] = xi;
}

// ---------------------------------------------------------------------------
// Scan pass 2 (PARALLEL): one block per p, one thread per chunk.
// Hillis-Steele inclusive scan of (A = Lambda^T, b = f) pairs in LDS,
// 8 steps; carry entering chunk c = inclusive[c-1] (exclusive shift).
// ---------------------------------------------------------------------------
__global__ __launch_bounds__(256) void k_scan2(
        const float* __restrict__ fr, const float* __restrict__ fi,
        const float* __restrict__ ltre, const float* __restrict__ ltim,
        float* __restrict__ cr, float* __restrict__ ci) {
    __shared__ float Ar[NCHUNK], Ai[NCHUNK], br[NCHUNK], bi[NCHUNK];
    const int p = blockIdx.x;
    const int c = threadIdx.x;
    const float lr = ltre[p], li = ltim[p];
    Ar[c] = lr; Ai[c] = li;
    br[c] = fr[c * PP + p];
    bi[c] = fi[c * PP + p];
    __syncthreads();
    #pragma unroll
    for (int d = 1; d < NCHUNK; d <<= 1) {
        float pAr = 0.f, pAi = 0.f, pbr = 0.f, pbi = 0.f;
        const bool has = (c >= d);
        if (has) { pAr = Ar[c-d]; pAi = Ai[c-d]; pbr = br[c-d]; pbi = bi[c-d]; }
        float cAr = Ar[c], cAi = Ai[c], cbr = br[c], cbi = bi[c];
        __syncthreads();
        if (has) {
            // (A_c,b_c) ∘ (A_{c-d},b_{c-d}): A = A_c*A_p ; b = A_c*b_p + b_c
            Ar[c] = cAr * pAr - cAi * pAi;
            Ai[c] = cAr * pAi + cAi * pAr;
            br[c] = cAr * pbr - cAi * pbi + cbr;
            bi[c] = cAr * pbi + cAi * pbr + cbi;
        }
        __syncthreads();
    }
    cr[c * PP + p] = (c == 0) ? 0.f : br[c-1];
    ci[c * PP + p] = (c == 0) ? 0.f : bi[c-1];
}

// ---------------------------------------------------------------------------
// Scan pass 3: replay with correct carry; overwrite Bu with xs (bf16, in-place).
// ---------------------------------------------------------------------------
__global__ void k_scan3(u16* __restrict__ bu,
                        const float* __restrict__ lbre, const float* __restrict__ lbim,
                        const float* __restrict__ cr, const float* __restrict__ ci) {
    int p = blockIdx.x * 256 + threadIdx.x;
    int c = blockIdx.y;
    float ar = lbre[p], ai = lbim[p];
    float xr = cr[c * PP + p], xi = ci[c * PP + p];
    u16* b = bu + (size_t)c * CHUNK * NP2 + p;
    for (int j = 0; j < CHUNK; j++) {
        float br = bf2f(b[0]), bi = bf2f(b[PP]);
        float nr = ar * xr - ai * xi + br;
        float ni = ar * xi + ai * xr + bi;
        xr = nr; xi = ni;
        b[0] = f2bf(xr);
        b[PP] = f2bf(xi);
        b += NP2;
    }
}

extern "C" void kernel_launch(void* const* d_in, const int* in_sizes, int n_in,
                              void* d_out, int out_size, void* d_ws, size_t ws_size,
                              hipStream_t stream) {
    const float* u       = (const float*)d_in[0];   // (L,H)
    const float* lre     = (const float*)d_in[1];   // (P,)
    const float* lim     = (const float*)d_in[2];   // (P,)
    const float* B       = (const float*)d_in[3];   // (P,H,2)
    const float* C       = (const float*)d_in[4];   // (H,P,2)
    const float* D       = (const float*)d_in[5];   // (H,)
    const float* logstep = (const float*)d_in[6];   // (P,)
    float* out = (float*)d_out;

    float* w = (float*)d_ws;
    float* gre  = w;
    float* gim  = w + 512;
    float* lbre = w + 1024;
    float* lbim = w + 1536;
    float* ltre = w + 2048;
    float* ltim = w + 2560;
    float* fr   = w + 4096;                       // NCHUNK*PP each
    float* fi   = fr + NCHUNK * PP;
    float* cr   = fi + NCHUNK * PP;
    float* ci   = cr + NCHUNK * PP;
    u16*   bub  = (u16*)(w + (1 << 20));          // L*2P bf16 = 32 MB (Bu -> xs in-place)
    u16*   ub   = bub + (size_t)LL * NP2;         // L*H bf16 = 32 MB
    u16*   bb   = ub + (size_t)LL * HH;           // 2P*H bf16 = 2 MB
    u16*   cp   = bb + (size_t)NP2 * HH;          // H*2P bf16 = 2 MB

    k_setup<<<1, 512, 0, stream>>>(lre, lim, logstep, gre, gim, lbre, lbim, ltre, ltim);
    k_bbar<<<(PP * HH) / 256, 256, 0, stream>>>(B, gre, gim, bb);
    k_cprep<<<(HH * PP) / 256, 256, 0, stream>>>(C, cp);
    k_cvt<<<(LL * HH) / 1024, 256, 0, stream>>>(u, ub);
    k_gemm<0><<<(NP2 / BN) * (LL / BM), 256, 0, stream>>>(ub, bb, bub, HH, nullptr, nullptr);
    k_scan1<<<dim3(PP / 256, NCHUNK), 256, 0, stream>>>(bub, lbre, lbim, fr, fi);
    k_scan2<<<PP, NCHUNK, 0, stream>>>(fr, fi, ltre, ltim, cr, ci);
    k_scan3<<<dim3(PP / 256, NCHUNK), 256, 0, stream>>>(bub, lbre, lbim, cr, ci);
    k_gemm<1><<<(HH / BN) * (LL / BM), 256, 0, stream>>>(bub, cp, out, NP2, ub, D);
}

// Round 5
// 269.025 us; speedup vs baseline: 6.0441x; 1.0015x over previous
//
#include <hip/hip_runtime.h>
#include <math.h>

#define LL 16384
#define HH 1024
#define PP 512
#define NP2 1024        // 2*PP (re|im concatenated)
#define CHUNK 64
#define NCHUNK 256
#define BM 128
#define BN 128
#define BK 32

typedef unsigned short u16;
typedef __attribute__((ext_vector_type(8))) short bf16x8;   // 8 bf16 = 4 VGPRs
typedef __attribute__((ext_vector_type(4))) float f32x4;

__device__ __forceinline__ u16 f2bf(float f) {
    unsigned u = __float_as_uint(f);
    unsigned r = 0x7fffu + ((u >> 16) & 1u);   // RNE
    return (u16)((u + r) >> 16);
}
__device__ __forceinline__ float bf2f(u16 x) {
    return __uint_as_float(((unsigned)x) << 16);
}

__device__ __forceinline__ void gload_lds16(const void* g, void* l) {
    __builtin_amdgcn_global_load_lds(
        (const __attribute__((address_space(1))) unsigned int*)g,
        (__attribute__((address_space(3))) unsigned int*)l, 16, 0, 0);
}

// ---------------------------------------------------------------------------
// Discretization constants per p.
// ---------------------------------------------------------------------------
__global__ void k_setup(const float* __restrict__ lre, const float* __restrict__ lim,
                        const float* __restrict__ logstep,
                        float* __restrict__ gre, float* __restrict__ gim,
                        float* __restrict__ lbre, float* __restrict__ lbim,
                        float* __restrict__ ltre, float* __restrict__ ltim) {
    int p = threadIdx.x;
    if (p >= PP) return;
    float dt = expf(logstep[p]);           // STEP_RESCALE = 1
    float ar = lre[p], ai = lim[p];
    float e = expf(ar * dt);
    float s, c;
    sincosf(ai * dt, &s, &c);
    float Lr = e * c, Li = e * s;          // Lambda_bar
    lbre[p] = Lr; lbim[p] = Li;
    float nr = Lr - 1.0f, ni = Li;
    float den = ar * ar + ai * ai;
    gre[p] = (nr * ar + ni * ai) / den;    // gamma = (Lambda_bar-1)/Lambda
    gim[p] = (ni * ar - nr * ai) / den;
    float tr = Lr, ti = Li;                // Lambda_bar^64 via 6 squarings
    for (int i = 0; i < 6; i++) {
        float rr = tr * tr - ti * ti;
        float mm = 2.0f * tr * ti;
        tr = rr; ti = mm;
    }
    ltre[p] = tr; ltim[p] = ti;
}

// ---------------------------------------------------------------------------
// Merged B_bar + C prep (one launch).
// blocks [0,2048): bb[p][h] planes (2P x H). blocks [2048,4096): cp (H x 2P).
// ---------------------------------------------------------------------------
__global__ void k_prep2(const float* __restrict__ B,
                        const float* __restrict__ gre, const float* __restrict__ gim,
                        const float* __restrict__ C,
                        u16* __restrict__ bb, u16* __restrict__ cp) {
    if (blockIdx.x < 2048) {
        int t = blockIdx.x * 256 + threadIdx.x;   // over P*H
        int p = t >> 10;
        float2 b = ((const float2*)B)[t];
        float gr = gre[p], gi = gim[p];
        bb[t] = f2bf(gr * b.x - gi * b.y);
        bb[(size_t)PP * HH + t] = f2bf(gr * b.y + gi * b.x);
    } else {
        int t = (blockIdx.x - 2048) * 256 + threadIdx.x;   // over H*P
        int h = t >> 9, p = t & 511;
        float2 c = ((const float2*)C)[t];
        cp[(size_t)h * NP2 + p] = f2bf(c.x);
        cp[(size_t)h * NP2 + PP + p] = f2bf(-c.y);
    }
}

// ---------------------------------------------------------------------------
// u fp32 -> bf16 (L x H), 4 elements/thread.
// ---------------------------------------------------------------------------
__global__ void k_cvt(const float* __restrict__ s, u16* __restrict__ d) {
    size_t i = ((size_t)blockIdx.x * 256 + threadIdx.x) * 4;
    float4 v = *(const float4*)&s[i];
    unsigned lo = (unsigned)f2bf(v.x) | ((unsigned)f2bf(v.y) << 16);
    unsigned hi = (unsigned)f2bf(v.z) | ((unsigned)f2bf(v.w) << 16);
    *(uint2*)&d[i] = make_uint2(lo, hi);
}

// ---------------------------------------------------------------------------
// bf16 MFMA GEMM_BT: C[M x N] = A[M x K] * Bt[N x K]^T,  N = 1024 (8 tiles).
// 128x128 tile, BK=32, 256 threads (4 waves, 2x2), global_load_lds width=16.
// XCD-aware swizzle: xcd = b&7 owns an M-tile band -> A fetched once per device.
// LDS XOR-swizzle: LDS[row][slot] holds global seg (slot ^ ((row>>1)&3));
//   staging keeps lane-contiguous LDS dest (global source permuted within 64B),
//   fragment reads at slot quad^((row>>1)&3) -> 2-way bank conflicts only.
// FUSE=0: bf16 store via LDS-assembled uint4 (full-line writes).
// FUSE=1: out = 2*acc + bf2f(ubf)*Din[col], fp32 direct store.
// ---------------------------------------------------------------------------
template<int FUSE>
__global__ __launch_bounds__(256) void k_gemm(
        const u16* __restrict__ A, const u16* __restrict__ Bt,
        void* __restrict__ outp, const int K,
        const u16* __restrict__ ubf, const float* __restrict__ Din) {
    __shared__ u16 smem[2 * BM * BK];   // 16 KB: lA | lB; reused by epilogue
    u16* lA = smem;
    u16* lB = smem + BM * BK;
    const int b = blockIdx.x;
    const int xcd = b & 7, s = b >> 3;
    const int m0 = (xcd * 16 + (s >> 3)) * BM;
    const int n0 = (s & 7) * BN;
    const int N = 8 * BN;
    const int t = threadIdx.x;
    const int lane = t & 63, wid = t >> 6;
    const int wm = (wid >> 1) * 64, wn = (wid & 1) * 64;
    const int frow = lane & 15, quad = lane >> 4;

    f32x4 acc[4][4];
    #pragma unroll
    for (int i = 0; i < 4; i++)
        #pragma unroll
        for (int j = 0; j < 4; j++) acc[i][j] = (f32x4){0.f, 0.f, 0.f, 0.f};

    // staging: thread t -> LDS offset t*16B (lane-contiguous, required by HW).
    // global source col-seg is XOR-swizzled: seg = slot ^ ((sr>>1)&3).
    // (sr+64 has the same xor since 64>>1 = 32 ≡ 0 mod 4.)
    const int sr = t >> 2, slot = t & 3;
    const int seg = slot ^ ((sr >> 1) & 3);
    const u16* gA = A + (size_t)(m0 + sr) * K + seg * 8;
    const u16* gB = Bt + (size_t)(n0 + sr) * K + seg * 8;
    u16* dA = &lA[sr * BK + slot * 8];
    u16* dB = &lB[sr * BK + slot * 8];

    for (int k0 = 0; k0 < K; k0 += BK) {
        __syncthreads();
        gload_lds16(gA + k0, dA);
        gload_lds16(gA + (size_t)64 * K + k0, dA + 64 * BK);
        gload_lds16(gB + k0, dB);
        gload_lds16(gB + (size_t)64 * K + k0, dB + 64 * BK);
        __syncthreads();
        bf16x8 av[4], bv[4];
        #pragma unroll
        for (int i = 0; i < 4; i++) {
            const int r = wm + i * 16 + frow;
            av[i] = *(const bf16x8*)&lA[r * BK + (quad ^ ((r >> 1) & 3)) * 8];
        }
        #pragma unroll
        for (int j = 0; j < 4; j++) {
            const int r = wn + j * 16 + frow;
            bv[j] = *(const bf16x8*)&lB[r * BK + (quad ^ ((r >> 1) & 3)) * 8];
        }
        #pragma unroll
        for (int i = 0; i < 4; i++)
            #pragma unroll
            for (int j = 0; j < 4; j++)
                acc[i][j] = __builtin_amdgcn_mfma_f32_16x16x32_bf16(
                    av[i], bv[j], acc[i][j], 0, 0, 0);
    }

    if (FUSE) {
        float* Cout = (float*)outp;
        #pragma unroll
        for (int i = 0; i < 4; i++) {
            const int row = m0 + wm + i * 16 + quad * 4;   // + r
            #pragma unroll
            for (int j = 0; j < 4; j++) {
                const int col = n0 + wn + j * 16 + frow;
                const float dv = Din[col];
                f32x4 v = acc[i][j];
                #pragma unroll
                for (int r = 0; r < 4; r++) {
                    const size_t o = (size_t)(row + r) * N + col;
                    Cout[o] = 2.0f * v[r] + bf2f(ubf[o]) * dv;
                }
            }
        }
    } else {
        // bf16 epilogue via LDS: 4 passes of 8 KB (rows {i*16..+15} x both halves),
        // then cooperative uint4 stores -> full-line writes.
        u16* Cb = (u16*)outp;
        const int half = wm >> 6;     // 0 or 1
        __syncthreads();              // MFMA ds_reads done; safe to reuse smem
        #pragma unroll
        for (int i = 0; i < 4; i++) {
            #pragma unroll
            for (int j = 0; j < 4; j++) {
                f32x4 v = acc[i][j];
                #pragma unroll
                for (int r = 0; r < 4; r++)
                    smem[half * 2048 + (quad * 4 + r) * 128 + wn + j * 16 + frow]
                        = f2bf(v[r]);
            }
            __syncthreads();
            #pragma unroll
            for (int c = 0; c < 2; c++) {
                const int fe = (t + c * 256) * 8;       // element offset, 8 u16 = 16B
                const int hh = fe >> 11, rem = fe & 2047;
                const int qr = rem >> 7, cb = rem & 127;
                const int row = m0 + hh * 64 + i * 16 + qr;
                *(uint4*)&Cb[(size_t)row * N + n0 + cb] = *(const uint4*)&smem[fe];
            }
            __syncthreads();
        }
    }
}

// ---------------------------------------------------------------------------
// Scan pass 1: per (p, chunk) local reduce, zero init -> chunk final.
// Bu layout: (L x 2P) bf16, re at col p, im at col 512+p. State fp32.
// ---------------------------------------------------------------------------
__global__ void k_scan1(const u16* __restrict__ bu,
                        const float* __restrict__ lbre, const float* __restrict__ lbim,
                        float* __restrict__ fr, float* __restrict__ fi) {
    int p = blockIdx.x * 256 + threadIdx.x;
    int c = blockIdx.y;
    float ar = lbre[p], ai = lbim[p];
    float xr = 0.f, xi = 0.f;
    const u16* b = bu + (size_t)c * CHUNK * NP2 + p;
    for (int j = 0; j < CHUNK; j++) {
        float br = bf2f(b[0]), bi = bf2f(b[PP]);
        float nr = ar * xr - ai * xi + br;
        float ni = ar * xi + ai * xr + bi;
        xr = nr; xi = ni;
        b += NP2;
    }
    fr[c * PP + p] = xr;
    fi[c * PP + p] = xi;
}

// ---------------------------------------------------------------------------
// Scan pass 2 (parallel): one block per p, one thread per chunk.
// Hillis-Steele inclusive scan of (A = Lambda^T, b = f) pairs in LDS.
// ---------------------------------------------------------------------------
__global__ __launch_bounds__(256) void k_scan2(
        const float* __restrict__ fr, const float* __restrict__ fi,
        const float* __restrict__ ltre, const float* __restrict__ ltim,
        float* __restrict__ cr, float* __restrict__ ci) {
    __shared__ float Ar[NCHUNK], Ai[NCHUNK], br[NCHUNK], bi[NCHUNK];
    const int p = blockIdx.x;
    const int c = threadIdx.x;
    const float lr = ltre[p], li = ltim[p];
    Ar[c] = lr; Ai[c] = li;
    br[c] = fr[c * PP + p];
    bi[c] = fi[c * PP + p];
    __syncthreads();
    #pragma unroll
    for (int d = 1; d < NCHUNK; d <<= 1) {
        float pAr = 0.f, pAi = 0.f, pbr = 0.f, pbi = 0.f;
        const bool has = (c >= d);
        if (has) { pAr = Ar[c-d]; pAi = Ai[c-d]; pbr = br[c-d]; pbi = bi[c-d]; }
        float cAr = Ar[c], cAi = Ai[c], cbr = br[c], cbi = bi[c];
        __syncthreads();
        if (has) {
            Ar[c] = cAr * pAr - cAi * pAi;
            Ai[c] = cAr * pAi + cAi * pAr;
            br[c] = cAr * pbr - cAi * pbi + cbr;
            bi[c] = cAr * pbi + cAi * pbr + cbi;
        }
        __syncthreads();
    }
    cr[c * PP + p] = (c == 0) ? 0.f : br[c-1];
    ci[c * PP + p] = (c == 0) ? 0.f : bi[c-1];
}

// ---------------------------------------------------------------------------
// Scan pass 3: replay with correct carry; overwrite Bu with xs (bf16, in-place).
// ---------------------------------------------------------------------------
__global__ void k_scan3(u16* __restrict__ bu,
                        const float* __restrict__ lbre, const float* __restrict__ lbim,
                        const float* __restrict__ cr, const float* __restrict__ ci) {
    int p = blockIdx.x * 256 + threadIdx.x;
    int c = blockIdx.y;
    float ar = lbre[p], ai = lbim[p];
    float xr = cr[c * PP + p], xi = ci[c * PP + p];
    u16* b = bu + (size_t)c * CHUNK * NP2 + p;
    for (int j = 0; j < CHUNK; j++) {
        float br = bf2f(b[0]), bi = bf2f(b[PP]);
        float nr = ar * xr - ai * xi + br;
        float ni = ar * xi + ai * xr + bi;
        xr = nr; xi = ni;
        b[0] = f2bf(xr);
        b[PP] = f2bf(xi);
        b += NP2;
    }
}

extern "C" void kernel_launch(void* const* d_in, const int* in_sizes, int n_in,
                              void* d_out, int out_size, void* d_ws, size_t ws_size,
                              hipStream_t stream) {
    const float* u       = (const float*)d_in[0];   // (L,H)
    const float* lre     = (const float*)d_in[1];   // (P,)
    const float* lim     = (const float*)d_in[2];   // (P,)
    const float* B       = (const float*)d_in[3];   // (P,H,2)
    const float* C       = (const float*)d_in[4];   // (H,P,2)
    const float* D       = (const float*)d_in[5];   // (H,)
    const float* logstep = (const float*)d_in[6];   // (P,)
    float* out = (float*)d_out;

    float* w = (float*)d_ws;
    float* gre  = w;
    float* gim  = w + 512;
    float* lbre = w + 1024;
    float* lbim = w + 1536;
    float* ltre = w + 2048;
    float* ltim = w + 2560;
    float* fr   = w + 4096;                       // NCHUNK*PP each
    float* fi   = fr + NCHUNK * PP;
    float* cr   = fi + NCHUNK * PP;
    float* ci   = cr + NCHUNK * PP;
    u16*   bub  = (u16*)(w + (1 << 20));          // L*2P bf16 = 32 MB (Bu -> xs in-place)
    u16*   ub   = bub + (size_t)LL * NP2;         // L*H bf16 = 32 MB
    u16*   bb   = ub + (size_t)LL * HH;           // 2P*H bf16 = 2 MB
    u16*   cp   = bb + (size_t)NP2 * HH;          // H*2P bf16 = 2 MB

    k_setup<<<1, 512, 0, stream>>>(lre, lim, logstep, gre, gim, lbre, lbim, ltre, ltim);
    k_prep2<<<4096, 256, 0, stream>>>(B, gre, gim, C, bb, cp);
    k_cvt<<<(LL * HH) / 1024, 256, 0, stream>>>(u, ub);
    k_gemm<0><<<(NP2 / BN) * (LL / BM), 256, 0, stream>>>(ub, bb, bub, HH, nullptr, nullptr);
    k_scan1<<<dim3(PP / 256, NCHUNK), 256, 0, stream>>>(bub, lbre, lbim, fr, fi);
    k_scan2<<<PP, NCHUNK, 0, stream>>>(fr, fi, ltre, ltim, cr, ci);
    k_scan3<<<dim3(PP / 256, NCHUNK), 256, 0, stream>>>(bub, lbre, lbim, cr, ci);
    k_gemm<1><<<(HH / BN) * (LL / BM), 256, 0, stream>>>(bub, cp, out, NP2, ub, D);
}

// Round 6
// 248.339 us; speedup vs baseline: 6.5476x; 1.0833x over previous
//
#include <hip/hip_runtime.h>
#include <math.h>

#define LL 16384
#define HH 1024
#define PP 512
#define NP2 1024        // 2*PP (re/im interleaved: col 2p = re, 2p+1 = im)
#define CHUNK 64
#define NCHUNK 256
#define BM 128
#define BN 128
#define BK 64

typedef unsigned short u16;
typedef __attribute__((ext_vector_type(8))) short bf16x8;   // 8 bf16 = 4 VGPRs
typedef __attribute__((ext_vector_type(4))) float f32x4;

__device__ __forceinline__ u16 f2bf(float f) {
    unsigned u = __float_as_uint(f);
    unsigned r = 0x7fffu + ((u >> 16) & 1u);   // RNE
    return (u16)((u + r) >> 16);
}
__device__ __forceinline__ float bf2f(u16 x) {
    return __uint_as_float(((unsigned)x) << 16);
}

__device__ __forceinline__ void gload_lds16(const void* g, void* l) {
    __builtin_amdgcn_global_load_lds(
        (const __attribute__((address_space(1))) unsigned int*)g,
        (__attribute__((address_space(3))) unsigned int*)l, 16, 0, 0);
}

// ---------------------------------------------------------------------------
// Discretization constants per p.
// ---------------------------------------------------------------------------
__global__ void k_setup(const float* __restrict__ lre, const float* __restrict__ lim,
                        const float* __restrict__ logstep,
                        float* __restrict__ gre, float* __restrict__ gim,
                        float* __restrict__ lbre, float* __restrict__ lbim,
                        float* __restrict__ ltre, float* __restrict__ ltim) {
    int p = threadIdx.x;
    if (p >= PP) return;
    float dt = expf(logstep[p]);           // STEP_RESCALE = 1
    float ar = lre[p], ai = lim[p];
    float e = expf(ar * dt);
    float s, c;
    sincosf(ai * dt, &s, &c);
    float Lr = e * c, Li = e * s;          // Lambda_bar
    lbre[p] = Lr; lbim[p] = Li;
    float nr = Lr - 1.0f, ni = Li;
    float den = ar * ar + ai * ai;
    gre[p] = (nr * ar + ni * ai) / den;    // gamma = (Lambda_bar-1)/Lambda
    gim[p] = (ni * ar - nr * ai) / den;
    float tr = Lr, ti = Li;                // Lambda_bar^64 via 6 squarings
    for (int i = 0; i < 6; i++) {
        float rr = tr * tr - ti * ti;
        float mm = 2.0f * tr * ti;
        tr = rr; ti = mm;
    }
    ltre[p] = tr; ltim[p] = ti;
}

// ---------------------------------------------------------------------------
// Merged B_bar + C prep (interleaved complex layout).
// bb row 2p = (gamma*B)_re, row 2p+1 = (gamma*B)_im.   (2P x H)
// cp col 2p = C_re, col 2p+1 = -C_im.                  (H x 2P)
// ---------------------------------------------------------------------------
__global__ void k_prep2(const float* __restrict__ B,
                        const float* __restrict__ gre, const float* __restrict__ gim,
                        const float* __restrict__ C,
                        u16* __restrict__ bb, u16* __restrict__ cp) {
    if (blockIdx.x < 2048) {
        int t = blockIdx.x * 256 + threadIdx.x;   // over P*H
        int p = t >> 10, h = t & 1023;
        float2 b = ((const float2*)B)[t];
        float gr = gre[p], gi = gim[p];
        bb[(size_t)(2 * p) * HH + h]     = f2bf(gr * b.x - gi * b.y);
        bb[(size_t)(2 * p + 1) * HH + h] = f2bf(gr * b.y + gi * b.x);
    } else {
        int t = (blockIdx.x - 2048) * 256 + threadIdx.x;   // over H*P
        int h = t >> 9, p = t & 511;
        float2 c = ((const float2*)C)[t];
        cp[(size_t)h * NP2 + 2 * p]     = f2bf(c.x);
        cp[(size_t)h * NP2 + 2 * p + 1] = f2bf(-c.y);
    }
}

// ---------------------------------------------------------------------------
// u fp32 -> bf16 (L x H), 4 elements/thread.
// ---------------------------------------------------------------------------
__global__ void k_cvt(const float* __restrict__ s, u16* __restrict__ d) {
    size_t i = ((size_t)blockIdx.x * 256 + threadIdx.x) * 4;
    float4 v = *(const float4*)&s[i];
    unsigned lo = (unsigned)f2bf(v.x) | ((unsigned)f2bf(v.y) << 16);
    unsigned hi = (unsigned)f2bf(v.z) | ((unsigned)f2bf(v.w) << 16);
    *(uint2*)&d[i] = make_uint2(lo, hi);
}

// ---------------------------------------------------------------------------
// bf16 MFMA GEMM_BT: C[M x N] = A[M x K] * Bt[N x K]^T,  N = 1024 (8 tiles).
// 128x128 tile, BK=64 (32 MFMA per barrier), 256 threads (4 waves, 2x2).
// XCD-aware swizzle: xcd = b&7 owns an M-tile band -> A fetched once/device.
// LDS XOR swizzle (full period 8): LDS[row][slot] holds global seg slot^(row&7);
// fragment reads slot (khalf*4+quad)^(frow&7) -> conflict-free.
// FUSE=0: bf16 store via LDS-assembled uint4 + FUSED per-chunk scan reduce
//         (chunk = 64 rows; BM = 2 chunks; block owns 64 complex p's).
// FUSE=1: out = 2*acc + bf2f(ubf)*Din[col], fp32 direct store.
// ---------------------------------------------------------------------------
template<int FUSE>
__global__ __launch_bounds__(256) void k_gemm(
        const u16* __restrict__ A, const u16* __restrict__ Bt,
        void* __restrict__ outp, const int K,
        const u16* __restrict__ ubf, const float* __restrict__ Din,
        const float* __restrict__ lbre, const float* __restrict__ lbim,
        float* __restrict__ frO, float* __restrict__ fiO) {
    __shared__ u16 smem[2 * BM * BK];   // 32 KB: lA | lB; reused by epilogue
    u16* lA = smem;
    u16* lB = smem + BM * BK;
    const int b = blockIdx.x;
    const int xcd = b & 7, s = b >> 3;
    const int m0 = (xcd * 16 + (s >> 3)) * BM;
    const int n0 = (s & 7) * BN;
    const int N = 8 * BN;
    const int t = threadIdx.x;
    const int lane = t & 63, wid = t >> 6;
    const int wm = (wid >> 1) * 64, wn = (wid & 1) * 64;
    const int frow = lane & 15, quad = lane >> 4;
    const int swz = frow & 7;

    f32x4 acc[4][4];
    #pragma unroll
    for (int i = 0; i < 4; i++)
        #pragma unroll
        for (int j = 0; j < 4; j++) acc[i][j] = (f32x4){0.f, 0.f, 0.f, 0.f};

    // staging: thread t -> LDS offset t*16B (lane-contiguous, HW requirement).
    // source col-seg = slot ^ (row&7); row groups +32 preserve (row&7).
    const int sr = t >> 3, slot = t & 7;
    const int seg = slot ^ (sr & 7);
    const u16* gA = A + (size_t)(m0 + sr) * K + seg * 8;
    const u16* gB = Bt + (size_t)(n0 + sr) * K + seg * 8;
    u16* dA = &lA[sr * BK + slot * 8];
    u16* dB = &lB[sr * BK + slot * 8];

    for (int k0 = 0; k0 < K; k0 += BK) {
        __syncthreads();
        #pragma unroll
        for (int g = 0; g < 4; g++) {
            gload_lds16(gA + (size_t)(32 * g) * K + k0, dA + 32 * g * BK);
            gload_lds16(gB + (size_t)(32 * g) * K + k0, dB + 32 * g * BK);
        }
        __syncthreads();
        #pragma unroll
        for (int kk = 0; kk < 2; kk++) {
            bf16x8 av[4], bv[4];
            #pragma unroll
            for (int i = 0; i < 4; i++)
                av[i] = *(const bf16x8*)&lA[(wm + i * 16 + frow) * BK
                                            + (((kk << 2) | quad) ^ swz) * 8];
            #pragma unroll
            for (int j = 0; j < 4; j++)
                bv[j] = *(const bf16x8*)&lB[(wn + j * 16 + frow) * BK
                                            + (((kk << 2) | quad) ^ swz) * 8];
            #pragma unroll
            for (int i = 0; i < 4; i++)
                #pragma unroll
                for (int j = 0; j < 4; j++)
                    acc[i][j] = __builtin_amdgcn_mfma_f32_16x16x32_bf16(
                        av[i], bv[j], acc[i][j], 0, 0, 0);
        }
    }

    if (FUSE) {
        float* Cout = (float*)outp;
        #pragma unroll
        for (int i = 0; i < 4; i++) {
            const int row = m0 + wm + i * 16 + quad * 4;   // + r
            #pragma unroll
            for (int j = 0; j < 4; j++) {
                const int col = n0 + wn + j * 16 + frow;
                const float dv = Din[col];
                f32x4 v = acc[i][j];
                #pragma unroll
                for (int r = 0; r < 4; r++) {
                    const size_t o = (size_t)(row + r) * N + col;
                    Cout[o] = 2.0f * v[r] + bf2f(ubf[o]) * dv;
                }
            }
        }
    } else {
        // bf16 epilogue via LDS slabs (16 rows x both halves per pass) with
        // uint4 full-line stores + fused per-chunk scan reduction.
        // Scan threads: t<128 -> half = t>>6, q = t&63, p = n0/2 + q.
        u16* Cb = (u16*)outp;
        unsigned* sm32 = (unsigned*)smem;
        const int half = wm >> 6;     // 0 or 1 (for acc writes)
        const int sq = t & 63, sh = t >> 6;     // scan thread coords (t<128)
        const int sp = (n0 >> 1) + sq;          // global p
        float sar = 0.f, sai = 0.f, sxr = 0.f, sxi = 0.f;
        if (t < 128) { sar = lbre[sp]; sai = lbim[sp]; }
        __syncthreads();              // MFMA ds_reads done; safe to reuse smem
        #pragma unroll
        for (int i = 0; i < 4; i++) {
            #pragma unroll
            for (int j = 0; j < 4; j++) {
                f32x4 v = acc[i][j];
                #pragma unroll
                for (int r = 0; r < 4; r++)
                    smem[half * 2048 + (quad * 4 + r) * 128 + wn + j * 16 + frow]
                        = f2bf(v[r]);
            }
            __syncthreads();
            #pragma unroll
            for (int c = 0; c < 2; c++) {
                const int fe = (t + c * 256) * 8;       // 8 u16 = 16B
                const int hh = fe >> 11, rem = fe & 2047;
                const int qr = rem >> 7, cb = rem & 127;
                const int row = m0 + hh * 64 + i * 16 + qr;
                *(uint4*)&Cb[(size_t)row * N + n0 + cb] = *(const uint4*)&smem[fe];
            }
            if (t < 128) {
                // scan 16 rows of this slab for complex pair q of half sh
                #pragma unroll
                for (int r = 0; r < 16; r++) {
                    unsigned v = sm32[sh * 1024 + r * 64 + sq];
                    float br = bf2f((u16)(v & 0xffff));
                    float bi = bf2f((u16)(v >> 16));
                    float nr = sar * sxr - sai * sxi + br;
                    float ni = sar * sxi + sai * sxr + bi;
                    sxr = nr; sxi = ni;
                }
            }
            __syncthreads();
        }
        if (t < 128) {
            const int chunk = (m0 >> 6) + sh;
            frO[chunk * PP + sp] = sxr;
            fiO[chunk * PP + sp] = sxi;
        }
    }
}

// ---------------------------------------------------------------------------
// Scan pass 2 (parallel): one block per p, one thread per chunk.
// Hillis-Steele inclusive scan of (A = Lambda^T, b = f) pairs in LDS.
// ---------------------------------------------------------------------------
__global__ __launch_bounds__(256) void k_scan2(
        const float* __restrict__ fr, const float* __restrict__ fi,
        const float* __restrict__ ltre, const float* __restrict__ ltim,
        float* __restrict__ cr, float* __restrict__ ci) {
    __shared__ float Ar[NCHUNK], Ai[NCHUNK], br[NCHUNK], bi[NCHUNK];
    const int p = blockIdx.x;
    const int c = threadIdx.x;
    const float lr = ltre[p], li = ltim[p];
    Ar[c] = lr; Ai[c] = li;
    br[c] = fr[c * PP + p];
    bi[c] = fi[c * PP + p];
    __syncthreads();
    #pragma unroll
    for (int d = 1; d < NCHUNK; d <<= 1) {
        float pAr = 0.f, pAi = 0.f, pbr = 0.f, pbi = 0.f;
        const bool has = (c >= d);
        if (has) { pAr = Ar[c-d]; pAi = Ai[c-d]; pbr = br[c-d]; pbi = bi[c-d]; }
        float cAr = Ar[c], cAi = Ai[c], cbr = br[c], cbi = bi[c];
        __syncthreads();
        if (has) {
            Ar[c] = cAr * pAr - cAi * pAi;
            Ai[c] = cAr * pAi + cAi * pAr;
            br[c] = cAr * pbr - cAi * pbi + cbr;
            bi[c] = cAr * pbi + cAi * pbr + cbi;
        }
        __syncthreads();
    }
    cr[c * PP + p] = (c == 0) ? 0.f : br[c-1];
    ci[c * PP + p] = (c == 0) ? 0.f : bi[c-1];
}

// ---------------------------------------------------------------------------
// Scan pass 3: replay with carry; overwrite Bu with xs in-place.
// Interleaved layout: one u32 = (re,im) bf16 pair per p -> coalesced.
// ---------------------------------------------------------------------------
__global__ void k_scan3(unsigned* __restrict__ bu,
                        const float* __restrict__ lbre, const float* __restrict__ lbim,
                        const float* __restrict__ cr, const float* __restrict__ ci) {
    int p = blockIdx.x * 256 + threadIdx.x;
    int c = blockIdx.y;
    float ar = lbre[p], ai = lbim[p];
    float xr = cr[c * PP + p], xi = ci[c * PP + p];
    unsigned* b = bu + (size_t)c * CHUNK * PP + p;   // PP u32 per row
    for (int j = 0; j < CHUNK; j++) {
        unsigned v = *b;
        float br = bf2f((u16)(v & 0xffff));
        float bi = bf2f((u16)(v >> 16));
        float nr = ar * xr - ai * xi + br;
        float ni = ar * xi + ai * xr + bi;
        xr = nr; xi = ni;
        *b = (unsigned)f2bf(xr) | ((unsigned)f2bf(xi) << 16);
        b += PP;
    }
}

extern "C" void kernel_launch(void* const* d_in, const int* in_sizes, int n_in,
                              void* d_out, int out_size, void* d_ws, size_t ws_size,
                              hipStream_t stream) {
    const float* u       = (const float*)d_in[0];   // (L,H)
    const float* lre     = (const float*)d_in[1];   // (P,)
    const float* lim     = (const float*)d_in[2];   // (P,)
    const float* B       = (const float*)d_in[3];   // (P,H,2)
    const float* C       = (const float*)d_in[4];   // (H,P,2)
    const float* D       = (const float*)d_in[5];   // (H,)
    const float* logstep = (const float*)d_in[6];   // (P,)
    float* out = (float*)d_out;

    float* w = (float*)d_ws;
    float* gre  = w;
    float* gim  = w + 512;
    float* lbre = w + 1024;
    float* lbim = w + 1536;
    float* ltre = w + 2048;
    float* ltim = w + 2560;
    float* fr   = w + 4096;                       // NCHUNK*PP each
    float* fi   = fr + NCHUNK * PP;
    float* cr   = fi + NCHUNK * PP;
    float* ci   = cr + NCHUNK * PP;
    u16*   bub  = (u16*)(w + (1 << 20));          // L*2P bf16 = 32 MB (Bu -> xs in-place)
    u16*   ub   = bub + (size_t)LL * NP2;         // L*H bf16 = 32 MB
    u16*   bb   = ub + (size_t)LL * HH;           // 2P*H bf16 = 2 MB
    u16*   cp   = bb + (size_t)NP2 * HH;          // H*2P bf16 = 2 MB

    k_setup<<<1, 512, 0, stream>>>(lre, lim, logstep, gre, gim, lbre, lbim, ltre, ltim);
    k_prep2<<<4096, 256, 0, stream>>>(B, gre, gim, C, bb, cp);
    k_cvt<<<(LL * HH) / 1024, 256, 0, stream>>>(u, ub);
    k_gemm<0><<<(NP2 / BN) * (LL / BM), 256, 0, stream>>>(
        ub, bb, bub, HH, nullptr, nullptr, lbre, lbim, fr, fi);
    k_scan2<<<PP, NCHUNK, 0, stream>>>(fr, fi, ltre, ltim, cr, ci);
    k_scan3<<<dim3(PP / 256, NCHUNK), 256, 0, stream>>>(
        (unsigned*)bub, lbre, lbim, cr, ci);
    k_gemm<1><<<(HH / BN) * (LL / BM), 256, 0, stream>>>(
        bub, cp, out, NP2, ub, D, nullptr, nullptr, nullptr, nullptr);
}